// Round 1
// 1041.650 us; speedup vs baseline: 1.1298x; 1.1298x over previous
//
#include <hip/hip_runtime.h>
#include <hip/hip_bf16.h>

#define B_ 256
#define S_ 512
#define H_ 512
#define E_ 128
#define V_ 30000
#define RNNIN_ 641

using bf16x8 = __attribute__((ext_vector_type(8))) short;
using f32x4  = __attribute__((ext_vector_type(4))) float;

__device__ __forceinline__ short f2bf(float f) {
  unsigned int u = __float_as_uint(f);
  u += 0x7fffu + ((u >> 16) & 1u);
  return (short)(u >> 16);
}

__device__ __forceinline__ float fast_tanh(float x) {
  x = fminf(10.f, fmaxf(-10.f, x));
  float t = __expf(2.f * x);
  return (t - 1.f) / (t + 1.f);
}

__device__ __forceinline__ float sigmoidf(float x) {
  return 1.f / (1.f + __expf(-x));
}

__device__ __forceinline__ void gload_lds16(const void* g, void* l) {
  __builtin_amdgcn_global_load_lds(
      (const __attribute__((address_space(1))) void*)g,
      (__attribute__((address_space(3))) void*)l, 16, 0, 0);
}

// ---------------------------------------------------------------------------
// Pack attn_w[H:] (K=512 x N=512 fp32, row-major) into MFMA-fragment order:
// Btf[(( (k>>5)*32 + (n>>4) )*4 + ((k>>3)&3))*16 + (n&15)]*8 + (k&7)
// With this layout, the B-slice for one BK=64 K-step of one 256-col n-block
// is two contiguous 16 KB runs -> global_load_lds staging is a linear copy.
// ---------------------------------------------------------------------------
__global__ __launch_bounds__(256) void pack_b(
    const float* __restrict__ in, unsigned short* __restrict__ out)
{
  int i = blockIdx.x * 256 + threadIdx.x;   // 262144 elements
  int k = i >> 9, n = i & 511;
  float v = in[i];
  int idx = ((((k >> 5) * 32 + (n >> 4)) * 4 + ((k >> 3) & 3)) * 16 + (n & 15)) * 8 + (k & 7);
  out[idx] = (unsigned short)f2bf(v);
}

// ---------------------------------------------------------------------------
// Generic small fp32 GEMM (kept for the small matmuls).
// ---------------------------------------------------------------------------
template<bool BT, bool RELU>
__global__ __launch_bounds__(256) void gemm_f32(
    const float* __restrict__ A, const float* __restrict__ Bm,
    const float* __restrict__ bias, float* __restrict__ C,
    int M, int N, int K)
{
  __shared__ float As[16][65];
  __shared__ float Bs[16][65];
  const int m0 = blockIdx.x * 64, n0 = blockIdx.y * 64;
  const int tid = threadIdx.x;
  const int tx = tid & 15, ty = tid >> 4;
  float acc[4][4] = {};
  for (int k0 = 0; k0 < K; k0 += 16) {
    __syncthreads();
    #pragma unroll
    for (int i = 0; i < 4; i++) {
      int e = tid + i * 256;
      int m = e >> 4, k = e & 15;
      float v = 0.f;
      if (m0 + m < M && k0 + k < K) v = A[(size_t)(m0 + m) * K + k0 + k];
      As[k][m] = v;
    }
    #pragma unroll
    for (int i = 0; i < 4; i++) {
      int e = tid + i * 256;
      if (BT) {
        int n = e >> 4, k = e & 15;
        float v = 0.f;
        if (n0 + n < N && k0 + k < K) v = Bm[(size_t)(n0 + n) * K + k0 + k];
        Bs[k][n] = v;
      } else {
        int k = e >> 6, n = e & 63;
        float v = 0.f;
        if (n0 + n < N && k0 + k < K) v = Bm[(size_t)(k0 + k) * N + n0 + n];
        Bs[k][n] = v;
      }
    }
    __syncthreads();
    #pragma unroll
    for (int k = 0; k < 16; k++) {
      float a[4], b[4];
      #pragma unroll
      for (int i = 0; i < 4; i++) a[i] = As[k][ty * 4 + i];
      #pragma unroll
      for (int j = 0; j < 4; j++) b[j] = Bs[k][tx * 4 + j];
      #pragma unroll
      for (int i = 0; i < 4; i++)
        #pragma unroll
        for (int j = 0; j < 4; j++) acc[i][j] += a[i] * b[j];
    }
  }
  #pragma unroll
  for (int i = 0; i < 4; i++) {
    int m = m0 + ty * 4 + i;
    if (m >= M) continue;
    #pragma unroll
    for (int j = 0; j < 4; j++) {
      int n = n0 + tx * 4 + j;
      if (n >= N) continue;
      float v = acc[i][j] + (bias ? bias[n] : 0.f);
      if (RELU) v = fmaxf(v, 0.f);
      C[(size_t)m * N + n] = v;
    }
  }
}

// BT=true body as a device function so gi & gh can share one launch (z-dim).
__device__ void gemm_bt_dev(float (*As)[65], float (*Bs)[65],
    const float* __restrict__ A, const float* __restrict__ Bm,
    const float* __restrict__ bias, float* __restrict__ C,
    int M, int N, int K)
{
  const int m0 = blockIdx.x * 64, n0 = blockIdx.y * 64;
  const int tid = threadIdx.x;
  const int tx = tid & 15, ty = tid >> 4;
  float acc[4][4] = {};
  for (int k0 = 0; k0 < K; k0 += 16) {
    __syncthreads();
    #pragma unroll
    for (int i = 0; i < 4; i++) {
      int e = tid + i * 256;
      int m = e >> 4, k = e & 15;
      float v = 0.f;
      if (m0 + m < M && k0 + k < K) v = A[(size_t)(m0 + m) * K + k0 + k];
      As[k][m] = v;
    }
    #pragma unroll
    for (int i = 0; i < 4; i++) {
      int e = tid + i * 256;
      int n = e >> 4, k = e & 15;
      float v = 0.f;
      if (n0 + n < N && k0 + k < K) v = Bm[(size_t)(n0 + n) * K + k0 + k];
      Bs[k][n] = v;
    }
    __syncthreads();
    #pragma unroll
    for (int k = 0; k < 16; k++) {
      float a[4], b[4];
      #pragma unroll
      for (int i = 0; i < 4; i++) a[i] = As[k][ty * 4 + i];
      #pragma unroll
      for (int j = 0; j < 4; j++) b[j] = Bs[k][tx * 4 + j];
      #pragma unroll
      for (int i = 0; i < 4; i++)
        #pragma unroll
        for (int j = 0; j < 4; j++) acc[i][j] += a[i] * b[j];
    }
  }
  #pragma unroll
  for (int i = 0; i < 4; i++) {
    int m = m0 + ty * 4 + i;
    if (m >= M) continue;
    #pragma unroll
    for (int j = 0; j < 4; j++) {
      int n = n0 + tx * 4 + j;
      if (n >= N) continue;
      C[(size_t)m * N + n] = acc[i][j] + bias[n];
    }
  }
}

__global__ __launch_bounds__(256) void gemm_gru(
    const float* __restrict__ xb, const float* __restrict__ w_ih,
    const float* __restrict__ b_ih, float* __restrict__ gi,
    const float* __restrict__ hid, const float* __restrict__ w_hh,
    const float* __restrict__ b_hh, float* __restrict__ gh)
{
  __shared__ float As[16][65];
  __shared__ float Bs[16][65];
  if (blockIdx.z == 0) gemm_bt_dev(As, Bs, xb, w_ih, b_ih, gi, B_, 1536, RNNIN_);
  else                 gemm_bt_dev(As, Bs, hid, w_hh, b_hh, gh, B_, 1536, H_);
}

// ---------------------------------------------------------------------------
// Attention GEMM fused with tanh(.)·v_w reduction into scores.
// A = enc (M=S*B, K=512) fp32.  Btf = attn_w[H:] pre-packed bf16 fragments.
// Tile 64m x 256n (N split in 2), BK=64, 256 threads / 4 waves (1 n-wave each).
// 2-phase loop: B staged via global_load_lds (linear, coalesced); A staged
// via reg (fp32->bf16 convert) with next-K prefetch kept in flight across
// the barrier (counted vmcnt(4), never a full drain in steady state).
// ---------------------------------------------------------------------------
__global__ __launch_bounds__(256, 3) void attn_gemm_score(
    const float* __restrict__ A, const unsigned short* __restrict__ Btf,
    const float* __restrict__ hid_pb, const float* __restrict__ v_w,
    float* __restrict__ scores)
{
  __shared__ short As[2 * 4 * 64 * 8];    // 8 KB  [ch][mg][ld][8]
  __shared__ short Bs[2 * 16 * 64 * 8];   // 32 KB [ch][ng][ld][8]

  // XCD-adjacent swizzle (4096 % 8 == 0): consecutive tiles share an XCD;
  // tiles (2t, 2t+1) share the same A panel -> second gets L2 hits.
  const int bid  = blockIdx.x;
  const int tile = (bid & 7) * 512 + (bid >> 3);
  const int mblk = tile >> 1, nblk = tile & 1;
  const int m0 = mblk * 64, n0 = nblk * 256;

  const int tid  = threadIdx.x;
  const int lane = tid & 63;
  const int wv   = tid >> 6;            // 0..3 = n-wave
  const int quad = lane >> 4, l15 = lane & 15;

  // A staging decode: thread -> (row 0..63, 16-float k-segment 0..3)
  const int arow = tid >> 2;
  const int aseg = tid & 3;
  const float* aptr = A + (size_t)(m0 + arow) * H_ + aseg * 16;
  const int ac = aseg >> 1, aq0 = (aseg & 1) * 2;
  short* aw0 = &As[((ac * 4 + (arow >> 4)) * 64 + aq0 * 16 + (arow & 15)) * 8];
  short* aw1 = aw0 + 16 * 8;

  const unsigned short* bsrc = Btf + nblk * 8192;

  f32x4 acc[4][4];
  #pragma unroll
  for (int i = 0; i < 4; i++)
    #pragma unroll
    for (int j = 0; j < 4; j++) acc[i][j] = f32x4{0.f, 0.f, 0.f, 0.f};

  float4 rA[4];
  #pragma unroll
  for (int i = 0; i < 4; i++) rA[i] = *(const float4*)(aptr + i * 4);

  for (int kt = 0; kt < 8; kt++) {
    __builtin_amdgcn_s_barrier();
    asm volatile("s_waitcnt vmcnt(0)" ::: "memory");   // rA (this kt) ready

    // issue B stage: 8 x global_load_lds, linear fragment copy (L2-resident)
    #pragma unroll
    for (int i = 0; i < 8; i++) {
      const unsigned short* g = bsrc + (kt * 2 + (i >> 2)) * 16384
                                     + ((i & 3) * 256 + tid) * 8;
      gload_lds16((const void*)g, (void*)&Bs[(i * 256 + wv * 64) * 8]);
    }

    // convert & write A fragments (2 x ds_write_b128)
    {
      bf16x8 f0, f1;
      f0[0] = f2bf(rA[0].x); f0[1] = f2bf(rA[0].y); f0[2] = f2bf(rA[0].z); f0[3] = f2bf(rA[0].w);
      f0[4] = f2bf(rA[1].x); f0[5] = f2bf(rA[1].y); f0[6] = f2bf(rA[1].z); f0[7] = f2bf(rA[1].w);
      f1[0] = f2bf(rA[2].x); f1[1] = f2bf(rA[2].y); f1[2] = f2bf(rA[2].z); f1[3] = f2bf(rA[2].w);
      f1[4] = f2bf(rA[3].x); f1[5] = f2bf(rA[3].y); f1[6] = f2bf(rA[3].z); f1[7] = f2bf(rA[3].w);
      *(bf16x8*)aw0 = f0;
      *(bf16x8*)aw1 = f1;
    }

    if (kt < 7) {
      asm volatile("" ::: "memory");    // keep A-prefetch AFTER the 8 B issues
      const float* anext = aptr + (kt + 1) * 64;
      #pragma unroll
      for (int i = 0; i < 4; i++) rA[i] = *(const float4*)(anext + i * 4);
      // wait: 8 B loads done; 4 A-prefetch loads remain in flight
      asm volatile("s_waitcnt vmcnt(4) lgkmcnt(0)" ::: "memory");
    } else {
      asm volatile("s_waitcnt vmcnt(0) lgkmcnt(0)" ::: "memory");
    }
    __builtin_amdgcn_s_barrier();
    asm volatile("" ::: "memory");

    #pragma unroll
    for (int ch = 0; ch < 2; ch++) {
      bf16x8 a[4], b[4];
      #pragma unroll
      for (int ti = 0; ti < 4; ti++)
        a[ti] = *(const bf16x8*)&As[((ch * 4 + ti) * 64 + lane) * 8];
      #pragma unroll
      for (int tj = 0; tj < 4; tj++)
        b[tj] = *(const bf16x8*)&Bs[((ch * 16 + wv * 4 + tj) * 64 + lane) * 8];
      #pragma unroll
      for (int ti = 0; ti < 4; ti++)
        #pragma unroll
        for (int tj = 0; tj < 4; tj++)
          acc[ti][tj] = __builtin_amdgcn_mfma_f32_16x16x32_bf16(a[ti], b[tj], acc[ti][tj], 0, 0, 0);
    }
  }

  // Epilogue: tanh(acc + hid_pb)·v_w, reduce 64 n per wave, then LDS-combine
  // the 4 n-waves -> ONE atomic per row per block (2 blocks per point).
  __syncthreads();
  float* part = (float*)As;  // reuse: [row 0..63][wv 0..3]
  #pragma unroll
  for (int ti = 0; ti < 4; ti++) {
    #pragma unroll
    for (int r = 0; r < 4; r++) {
      int m = m0 + ti * 16 + quad * 4 + r;
      int b = m & (B_ - 1);
      float sum = 0.f;
      #pragma unroll
      for (int tj = 0; tj < 4; tj++) {
        int n = n0 + wv * 64 + tj * 16 + l15;
        float v = acc[ti][tj][r] + hid_pb[b * H_ + n];
        sum += fast_tanh(v) * v_w[n];
      }
      sum += __shfl_xor(sum, 1);
      sum += __shfl_xor(sum, 2);
      sum += __shfl_xor(sum, 4);
      sum += __shfl_xor(sum, 8);
      if (l15 == 0) part[(ti * 16 + quad * 4 + r) * 4 + wv] = sum;
    }
  }
  __syncthreads();
  if (tid < 64) {
    float s4 = part[tid * 4 + 0] + part[tid * 4 + 1] + part[tid * 4 + 2] + part[tid * 4 + 3];
    int m = m0 + tid;
    atomicAdd(scores + (m & (B_ - 1)) * S_ + (m >> 8), s4);
  }
}

// ---------------------------------------------------------------------------
// Logits GEMM: C(256,30000) = h1 @ fc_id_w + b.  (unchanged)
// ---------------------------------------------------------------------------
__global__ __launch_bounds__(256, 4) void logits_gemm(
    const unsigned short* __restrict__ Ab, const float* __restrict__ Bw,
    const float* __restrict__ bias, float* __restrict__ C)
{
  __shared__ short As[2 * 16 * 64 * 8];   // [c][mt][lane][8] = 32 KB
  __shared__ short Bs[2 * 4 * 64 * 8];    // [c][tj][lane][8] = 8 KB
  const int n0 = blockIdx.x * 64;
  const int tid = threadIdx.x;
  const int lane = tid & 63;
  const int wv = tid >> 6;
  const int quad = lane >> 4, l15 = lane & 15;

  f32x4 acc[4][4];
  #pragma unroll
  for (int i = 0; i < 4; i++)
    #pragma unroll
    for (int j = 0; j < 4; j++) acc[i][j] = f32x4{0.f, 0.f, 0.f, 0.f};

  const int nB  = tid & 63;
  const int kg  = tid >> 6;
  const int cB  = kg >> 1;
  const int q0  = (kg & 1) * 2;
  const int tjB = nB >> 4;
  const bool nOK = (n0 + nB) < V_;

  for (int kt = 0; kt < 8; kt++) {
    const int kb = kt * 64;
    __syncthreads();
    #pragma unroll
    for (int p = 0; p < 8; p++) {
      int m = p * 32 + (tid >> 3), f = tid & 7;
      int c = f >> 2, q = f & 3;
      bf16x8 v = *(const bf16x8*)(Ab + (size_t)m * H_ + kb + c * 32 + q * 8);
      int mt = m >> 4, ld = q * 16 + (m & 15);
      *(bf16x8*)&As[((c * 16 + mt) * 64 + ld) * 8] = v;
    }
    {
      float col[16];
      const float* src = Bw + (size_t)(kb + kg * 16) * V_ + n0 + nB;
      #pragma unroll
      for (int i = 0; i < 16; i++) col[i] = nOK ? src[(size_t)i * V_] : 0.f;
      bf16x8 f0, f1;
      #pragma unroll
      for (int i = 0; i < 8; i++) { f0[i] = f2bf(col[i]); f1[i] = f2bf(col[8 + i]); }
      int ld0 = q0 * 16 + (nB & 15);
      *(bf16x8*)&Bs[((cB * 4 + tjB) * 64 + ld0) * 8] = f0;
      *(bf16x8*)&Bs[((cB * 4 + tjB) * 64 + ld0 + 16) * 8] = f1;
    }
    __syncthreads();
    #pragma unroll
    for (int c = 0; c < 2; c++) {
      bf16x8 a[4], b[4];
      #pragma unroll
      for (int ti = 0; ti < 4; ti++)
        a[ti] = *(const bf16x8*)&As[((c * 16 + wv * 4 + ti) * 64 + lane) * 8];
      #pragma unroll
      for (int tj = 0; tj < 4; tj++)
        b[tj] = *(const bf16x8*)&Bs[((c * 4 + tj) * 64 + lane) * 8];
      #pragma unroll
      for (int ti = 0; ti < 4; ti++)
        #pragma unroll
        for (int tj = 0; tj < 4; tj++)
          acc[ti][tj] = __builtin_amdgcn_mfma_f32_16x16x32_bf16(a[ti], b[tj], acc[ti][tj], 0, 0, 0);
    }
  }
  #pragma unroll
  for (int ti = 0; ti < 4; ti++)
    #pragma unroll
    for (int r = 0; r < 4; r++) {
      int m = wv * 64 + ti * 16 + quad * 4 + r;
      #pragma unroll
      for (int tj = 0; tj < 4; tj++) {
        int n = n0 + tj * 16 + l15;
        if (n < V_) C[(size_t)m * V_ + n] = acc[ti][tj][r] + bias[n];
      }
    }
}

// --------------------------- small kernels ---------------------------------
__global__ __launch_bounds__(256) void attn_softmax(
    const float* __restrict__ scores, const int* __restrict__ mask, float* __restrict__ aw)
{
  int b = blockIdx.x, tid = threadIdx.x;
  __shared__ float red[256];
  float v0 = scores[b * S_ + tid];
  float v1 = scores[b * S_ + tid + 256];
  if (mask[b * S_ + tid] == 0) v0 = -1e10f;
  if (mask[b * S_ + tid + 256] == 0) v1 = -1e10f;
  red[tid] = fmaxf(v0, v1);
  __syncthreads();
  for (int off = 128; off; off >>= 1) { if (tid < off) red[tid] = fmaxf(red[tid], red[tid + off]); __syncthreads(); }
  float mx = red[0];
  __syncthreads();
  float e0 = __expf(v0 - mx), e1 = __expf(v1 - mx);
  red[tid] = e0 + e1;
  __syncthreads();
  for (int off = 128; off; off >>= 1) { if (tid < off) red[tid] += red[tid + off]; __syncthreads(); }
  float inv = 1.f / red[0];
  aw[b * S_ + tid] = e0 * inv;
  aw[b * S_ + tid + 256] = e1 * inv;
}

// S split into 4 chunks -> 1024 blocks; deterministic partials into wpart.
__global__ __launch_bounds__(512) void attn_weighted_part(
    const float* __restrict__ aw, const float* __restrict__ enc, float* __restrict__ wpart)
{
  int b = blockIdx.x, c = blockIdx.y, h = threadIdx.x;
  __shared__ float a_s[128];
  if (h < 128) a_s[h] = aw[b * S_ + c * 128 + h];
  __syncthreads();
  const float* ep = enc + ((size_t)(c * 128) * B_ + b) * H_ + h;
  float acc = 0.f;
  #pragma unroll 8
  for (int s = 0; s < 128; s++)
    acc += a_s[s] * ep[(size_t)s * B_ * H_];
  wpart[((size_t)c * B_ + b) * H_ + h] = acc;
}

__global__ void build_x(const float* __restrict__ wpart, const int* __restrict__ ids,
                        const float* __restrict__ emb, const float* __restrict__ rate,
                        float* __restrict__ x)
{
  int i = blockIdx.x * 256 + threadIdx.x;
  if (i >= B_ * RNNIN_) return;
  int b = i / RNNIN_, j = i % RNNIN_;
  float v;
  if (j < H_) {
    size_t o = (size_t)b * H_ + j;
    const size_t st = (size_t)B_ * H_;
    v = wpart[o] + wpart[o + st] + wpart[o + 2 * st] + wpart[o + 3 * st];
  }
  else if (j < H_ + E_) v = emb[(size_t)ids[b] * E_ + (j - H_)];
  else v = rate[b];
  x[i] = v;
}

__global__ void gru_gates(const float* __restrict__ gi, const float* __restrict__ gh,
                          const float* __restrict__ h0, float* __restrict__ h1,
                          unsigned short* __restrict__ h1b, float* __restrict__ h1_out)
{
  int i = blockIdx.x * 256 + threadIdx.x;  // B*H
  int b = i >> 9, j = i & (H_ - 1);
  const float* gib = gi + (size_t)b * 1536;
  const float* ghb = gh + (size_t)b * 1536;
  float r = sigmoidf(gib[j] + ghb[j]);
  float z = sigmoidf(gib[512 + j] + ghb[512 + j]);
  float n = fast_tanh(gib[1024 + j] + r * ghb[1024 + j]);
  float h = (1.f - z) * n + z * h0[i];
  h1[i] = h;
  h1b[i] = (unsigned short)f2bf(h);
  h1_out[i] = h;
}

__global__ __launch_bounds__(1024) void softmax_fused(
    float* __restrict__ lp, const float* __restrict__ cv, int* __restrict__ maxid)
{
  int b = blockIdx.x, tid = threadIdx.x;
  int wid = tid >> 6, lane = tid & 63;
  float* row = lp + (size_t)b * V_;
  const float* cvr = cv + (size_t)b * V_;
  __shared__ float redf[16];
  __shared__ float rede[16];
  __shared__ int   redi[16];

  float mx = -INFINITY;
  for (int v = tid; v < V_; v += 1024) mx = fmaxf(mx, row[v]);
  #pragma unroll
  for (int o = 1; o < 64; o <<= 1) mx = fmaxf(mx, __shfl_xor(mx, o));
  if (lane == 0) redf[wid] = mx;
  __syncthreads();
  if (tid == 0) {
    float m = redf[0];
    for (int i = 1; i < 16; i++) m = fmaxf(m, redf[i]);
    redf[0] = m;
  }
  __syncthreads();
  float M = redf[0];
  __syncthreads();

  float s = 0.f, best = -1.f;
  int bi = 0;
  for (int v = tid; v < V_; v += 1024) {
    float e = __expf(row[v] - M) * cvr[v];
    row[v] = e;
    s += e;
    if (e > best) { best = e; bi = v; }
  }
  #pragma unroll
  for (int o = 1; o < 64; o <<= 1) {
    s += __shfl_xor(s, o);
    float ob = __shfl_xor(best, o);
    int oi = __shfl_xor(bi, o);
    if (ob > best || (ob == best && oi < bi)) { best = ob; bi = oi; }
  }
  if (lane == 0) { redf[wid] = s; rede[wid] = best; redi[wid] = bi; }
  __syncthreads();
  if (tid == 0) {
    float ss = 0.f, bb = rede[0];
    int ii = redi[0];
    for (int i = 0; i < 16; i++) {
      ss += redf[i];
      if (rede[i] > bb || (rede[i] == bb && redi[i] < ii)) { bb = rede[i]; ii = redi[i]; }
    }
    redf[0] = ss;
    maxid[b] = ii;
  }
  __syncthreads();
  float inv = 1.f / redf[0];
  for (int v = tid; v < V_; v += 1024) {
    float p = row[v] * inv;
    p = fminf(fmaxf(p, 1e-6f), 1.f);
    row[v] = __logf(p);
  }
}

__global__ void build_tandem(const int* __restrict__ maxid, const float* __restrict__ emb,
                             const float* __restrict__ h1, float* __restrict__ t)
{
  int i = blockIdx.x * 256 + threadIdx.x;  // B*640
  if (i >= B_ * 640) return;
  int b = i / 640, j = i % 640;
  t[i] = (j < E_) ? emb[(size_t)maxid[b] * E_ + j] : h1[b * H_ + (j - E_)];
}

__global__ __launch_bounds__(64) void rate_head(const float* __restrict__ rate_in,
                                                const float* __restrict__ rate_w,
                                                const float* __restrict__ rate_b,
                                                float* __restrict__ out)
{
  int b = blockIdx.x, t = threadIdx.x;
  float s = 0.f;
  #pragma unroll
  for (int i = 0; i < 8; i++) s += rate_in[b * H_ + t + 64 * i] * rate_w[t + 64 * i];
  #pragma unroll
  for (int m = 32; m; m >>= 1) s += __shfl_xor(s, m);
  if (t == 0) out[b] = sigmoidf(s + rate_b[0]);
}

// ---------------------------------------------------------------------------
extern "C" void kernel_launch(void* const* d_in, const int* in_sizes, int n_in,
                              void* d_out, int out_size, void* d_ws, size_t ws_size,
                              hipStream_t stream)
{
  const int*   input_id   = (const int*)  d_in[0];
  const float* input_rate = (const float*)d_in[1];
  const float* hidden     = (const float*)d_in[2];
  const float* enc        = (const float*)d_in[3];
  const int*   attn_mask  = (const int*)  d_in[4];
  const float* cv         = (const float*)d_in[5];
  const float* emb        = (const float*)d_in[6];
  const float* attn_w     = (const float*)d_in[7];
  const float* attn_b     = (const float*)d_in[8];
  const float* v_w        = (const float*)d_in[9];
  const float* w_ih       = (const float*)d_in[10];
  const float* w_hh       = (const float*)d_in[11];
  const float* b_ih       = (const float*)d_in[12];
  const float* b_hh       = (const float*)d_in[13];
  const float* fc_w       = (const float*)d_in[14];
  const float* fc_b       = (const float*)d_in[15];
  const float* tan_w      = (const float*)d_in[16];
  const float* tan_b      = (const float*)d_in[17];
  const float* rate_w     = (const float*)d_in[18];
  const float* rate_b     = (const float*)d_in[19];

  float* out = (float*)d_out;
  float* ws  = (float*)d_ws;
  // ws layout (float offsets), same 7.74 MB footprint as before.
  float* hid_pb   = ws;                   // [0,       131072)
  float* scores   = ws + 131072;          // [131072,  262144)
  float* aw       = ws + 262144;          // [262144,  393216)
  float* weighted = ws + 393216;          // unused now (kept for layout)
  float* xbuf     = ws + 524288;          // [524288,  688384)  B*641
  float* gi       = ws + 688384;          // [688384, 1081600)  B*1536
  float* gh       = ws + 1081600;         // [1081600,1474816)  B*1536
  float* h1       = ws + 1474816;         // [1474816,1605888)  B*H
  float* rate_in  = ws + 1605888;         // [1605888,1736960)  B*H
  int*   maxid    = (int*)(ws + 1736960); // [1736960,1737216)  B ints
  unsigned short* Btf = (unsigned short*)(ws + 1737216); // 512KB packed B
  unsigned short* h1b = (unsigned short*)(ws + 1868288); // 256*512 bf16
  // wpart (4*B*H floats = 2 MB) overlays gi+gh: consumed by build_x BEFORE
  // gemm_gru writes gi/gh.
  float* wpart = gi;

  float* out_pred = out;
  float* out_rate = out + (size_t)B_ * V_;
  float* out_h1   = out + (size_t)B_ * V_ + B_;
  (void)weighted;

  pack_b<<<1024, 256, 0, stream>>>(attn_w + (size_t)H_ * H_, Btf);

  hipMemsetAsync(scores, 0, (size_t)B_ * S_ * sizeof(float), stream);

  gemm_f32<false, false><<<dim3(4, 8), 256, 0, stream>>>(hidden, attn_w, attn_b, hid_pb, B_, H_, H_);

  attn_gemm_score<<<4096, 256, 0, stream>>>(enc, Btf, hid_pb, v_w, scores);

  attn_softmax<<<B_, 256, 0, stream>>>(scores, attn_mask, aw);
  attn_weighted_part<<<dim3(B_, 4), 512, 0, stream>>>(aw, enc, wpart);
  build_x<<<641, 256, 0, stream>>>(wpart, input_id, emb, input_rate, xbuf);

  gemm_gru<<<dim3(4, 24, 2), 256, 0, stream>>>(xbuf, w_ih, b_ih, gi, hidden, w_hh, b_hh, gh);
  gru_gates<<<512, 256, 0, stream>>>(gi, gh, hidden, h1, h1b, out_h1);

  logits_gemm<<<469, 256, 0, stream>>>(h1b, fc_w, fc_b, out_pred);
  softmax_fused<<<B_, 1024, 0, stream>>>(out_pred, cv, maxid);

  build_tandem<<<640, 256, 0, stream>>>(maxid, emb, h1, xbuf);
  gemm_f32<false, true><<<dim3(4, 8), 256, 0, stream>>>(xbuf, tan_w, tan_b, rate_in, B_, H_, 640);
  rate_head<<<B_, 64, 0, stream>>>(rate_in, rate_w, rate_b, out_rate);
}

// Round 3
// 1004.484 us; speedup vs baseline: 1.1716x; 1.0370x over previous
//
#include <hip/hip_runtime.h>
#include <hip/hip_bf16.h>

#define B_ 256
#define S_ 512
#define H_ 512
#define E_ 128
#define V_ 30000
#define RNNIN_ 641

using bf16x8 = __attribute__((ext_vector_type(8))) short;
using f32x4  = __attribute__((ext_vector_type(4))) float;

__device__ __forceinline__ short f2bf(float f) {
  unsigned int u = __float_as_uint(f);
  u += 0x7fffu + ((u >> 16) & 1u);
  return (short)(u >> 16);
}

__device__ __forceinline__ float fast_tanh(float x) {
  x = fminf(10.f, fmaxf(-10.f, x));
  float t = __expf(2.f * x);
  return (t - 1.f) / (t + 1.f);
}

__device__ __forceinline__ float sigmoidf(float x) {
  return 1.f / (1.f + __expf(-x));
}

// ---------------------------------------------------------------------------
// Shared fp32 tile-GEMM bodies (proven; used for the small matmuls).
// ---------------------------------------------------------------------------
__device__ void gemm_nn_dev(float (*As)[65], float (*Bs)[65],
    const float* __restrict__ A, const float* __restrict__ Bm,
    const float* __restrict__ bias, float* __restrict__ C,
    int M, int N, int K, int m0, int n0)
{
  const int tid = threadIdx.x;
  const int tx = tid & 15, ty = tid >> 4;
  float acc[4][4] = {};
  for (int k0 = 0; k0 < K; k0 += 16) {
    __syncthreads();
    #pragma unroll
    for (int i = 0; i < 4; i++) {
      int e = tid + i * 256;
      int m = e >> 4, k = e & 15;
      float v = 0.f;
      if (m0 + m < M && k0 + k < K) v = A[(size_t)(m0 + m) * K + k0 + k];
      As[k][m] = v;
    }
    #pragma unroll
    for (int i = 0; i < 4; i++) {
      int e = tid + i * 256;
      int k = e >> 6, n = e & 63;
      float v = 0.f;
      if (n0 + n < N && k0 + k < K) v = Bm[(size_t)(k0 + k) * N + n0 + n];
      Bs[k][n] = v;
    }
    __syncthreads();
    #pragma unroll
    for (int k = 0; k < 16; k++) {
      float a[4], b[4];
      #pragma unroll
      for (int i = 0; i < 4; i++) a[i] = As[k][ty * 4 + i];
      #pragma unroll
      for (int j = 0; j < 4; j++) b[j] = Bs[k][tx * 4 + j];
      #pragma unroll
      for (int i = 0; i < 4; i++)
        #pragma unroll
        for (int j = 0; j < 4; j++) acc[i][j] += a[i] * b[j];
    }
  }
  #pragma unroll
  for (int i = 0; i < 4; i++) {
    int m = m0 + ty * 4 + i;
    if (m >= M) continue;
    #pragma unroll
    for (int j = 0; j < 4; j++) {
      int n = n0 + tx * 4 + j;
      if (n >= N) continue;
      C[(size_t)m * N + n] = acc[i][j] + bias[n];
    }
  }
}

__device__ void gemm_bt_dev(float (*As)[65], float (*Bs)[65],
    const float* __restrict__ A, const float* __restrict__ Bm,
    const float* __restrict__ bias, float* __restrict__ C,
    int M, int N, int K)
{
  const int m0 = blockIdx.x * 64, n0 = blockIdx.y * 64;
  const int tid = threadIdx.x;
  const int tx = tid & 15, ty = tid >> 4;
  float acc[4][4] = {};
  for (int k0 = 0; k0 < K; k0 += 16) {
    __syncthreads();
    #pragma unroll
    for (int i = 0; i < 4; i++) {
      int e = tid + i * 256;
      int m = e >> 4, k = e & 15;
      float v = 0.f;
      if (m0 + m < M && k0 + k < K) v = A[(size_t)(m0 + m) * K + k0 + k];
      As[k][m] = v;
    }
    #pragma unroll
    for (int i = 0; i < 4; i++) {
      int e = tid + i * 256;
      int n = e >> 4, k = e & 15;
      float v = 0.f;
      if (n0 + n < N && k0 + k < K) v = Bm[(size_t)(n0 + n) * K + k0 + k];
      Bs[k][n] = v;
    }
    __syncthreads();
    #pragma unroll
    for (int k = 0; k < 16; k++) {
      float a[4], b[4];
      #pragma unroll
      for (int i = 0; i < 4; i++) a[i] = As[k][ty * 4 + i];
      #pragma unroll
      for (int j = 0; j < 4; j++) b[j] = Bs[k][tx * 4 + j];
      #pragma unroll
      for (int i = 0; i < 4; i++)
        #pragma unroll
        for (int j = 0; j < 4; j++) acc[i][j] += a[i] * b[j];
    }
  }
  #pragma unroll
  for (int i = 0; i < 4; i++) {
    int m = m0 + ty * 4 + i;
    if (m >= M) continue;
    #pragma unroll
    for (int j = 0; j < 4; j++) {
      int n = n0 + tx * 4 + j;
      if (n >= N) continue;
      C[(size_t)m * N + n] = acc[i][j] + bias[n];
    }
  }
}

// ---------------------------------------------------------------------------
// prep: blocks [0,1024) pack attn_w[H:] into MFMA-fragment order (bf16);
//       blocks [1024,1056) compute hid_pb = h0 @ attn_w[:H] + attn_b.
// Fragment layout: frag (kc32 = k>>5, nf = n>>4) is 1 KB contiguous at
// Btf + (kc32*32+nf)*512 shorts, lane-ordered: lane l -> n=nf*16+(l&15),
// k = kc32*32 + (l>>4)*8 .. +8.
// ---------------------------------------------------------------------------
__global__ __launch_bounds__(256) void prep_fused(
    const float* __restrict__ attn_w, unsigned short* __restrict__ Btf,
    const float* __restrict__ hidden, const float* __restrict__ attn_b,
    float* __restrict__ hid_pb)
{
  __shared__ float As[16][65];
  __shared__ float Bs[16][65];
  int bid = blockIdx.x;
  if (bid < 1024) {
    int i = bid * 256 + threadIdx.x;   // 262144 elements of attn_w[H:]
    int k = i >> 9, n = i & 511;
    float v = attn_w[(size_t)H_ * H_ + i];
    int idx = ((((k >> 5) * 32 + (n >> 4)) * 4 + ((k >> 3) & 3)) * 16 + (n & 15)) * 8 + (k & 7);
    Btf[idx] = (unsigned short)f2bf(v);
  } else {
    int bb = bid - 1024;
    gemm_nn_dev(As, Bs, hidden, attn_w, attn_b, hid_pb, B_, H_, H_,
                (bb & 3) * 64, (bb >> 2) * 64);
  }
}

// ---------------------------------------------------------------------------
// Attention GEMM fused with tanh(.)·v_w reduction into scores.
// A = enc (M=S*B, K=512) fp32.  Btf = packed bf16 fragments (B direct
// from L2 into registers -- no LDS round-trip, no DMA).
// Tile 64m x 256n, BK=64, 256 threads / 4 waves, each wave 64m x 64n.
// Only A goes through LDS (fp32->bf16 cvt), double-buffered.
// One raw s_barrier per kt fenced with lgkmcnt(0) ONLY: A-prefetch (HBM)
// and B loads (L2) stay in flight across the barrier; compiler inserts
// counted vmcnt waits at their uses.
// NOTE: no min-waves bound -- register-resident B needs ~190 VGPR; a
// (256,3) bound would cap at 170 and force scratch spills.
// ---------------------------------------------------------------------------
__global__ __launch_bounds__(256) void attn_gemm_score(
    const float* __restrict__ A, const unsigned short* __restrict__ Btf,
    const float* __restrict__ hid_pb, const float* __restrict__ v_w,
    float* __restrict__ scores)
{
  __shared__ short As[2 * 4096];        // 16 KB: [buf][ (kc*4+mi)*64 + slot ][8]

  // XCD-adjacent swizzle: consecutive tiles on one XCD; (2t,2t+1) share A panel.
  const int bid  = blockIdx.x;
  const int tile = (bid & 7) * 512 + (bid >> 3);
  const int mblk = tile >> 1, nblk = tile & 1;
  const int m0 = mblk * 64, n0 = nblk * 256;

  const int tid  = threadIdx.x;
  const int lane = tid & 63;
  const int wv   = tid >> 6;            // 0..3 = n-wave
  const int quad = lane >> 4, l15 = lane & 15;

  // A staging decode: thread -> (row 0..63, 16-float k-segment 0..3)
  const int arow = tid >> 2, aseg = tid & 3;
  const float* aptr = A + (size_t)(m0 + arow) * H_ + aseg * 16;
  const int ac = aseg >> 1, aq0 = (aseg & 1) * 2;
  short* aw0 = &As[((ac * 4 + (arow >> 4)) * 64 + aq0 * 16 + (arow & 15)) * 8];

  const int nf0 = nblk * 16 + wv * 4;   // first n-fragment index for this wave

  f32x4 acc[4][4];
  #pragma unroll
  for (int i = 0; i < 4; i++)
    #pragma unroll
    for (int j = 0; j < 4; j++) acc[i][j] = f32x4{0.f, 0.f, 0.f, 0.f};

  float4 rA[4];
  #pragma unroll
  for (int i = 0; i < 4; i++) rA[i] = *(const float4*)(aptr + i * 4);

  #pragma unroll
  for (int kt = 0; kt < 8; kt++) {
    // B fragments: per-lane dwordx4 straight from L2 (packed layout).
    bf16x8 b[2][4];
    #pragma unroll
    for (int kc = 0; kc < 2; kc++)
      #pragma unroll
      for (int tj = 0; tj < 4; tj++)
        b[kc][tj] = *(const bf16x8*)(Btf + (((kt * 2 + kc) * 32 + nf0 + tj) << 9) + lane * 8);

    // convert & write A(kt) into buf kt&1 (2 x ds_write_b128)
    {
      bf16x8 f0, f1;
      f0[0] = f2bf(rA[0].x); f0[1] = f2bf(rA[0].y); f0[2] = f2bf(rA[0].z); f0[3] = f2bf(rA[0].w);
      f0[4] = f2bf(rA[1].x); f0[5] = f2bf(rA[1].y); f0[6] = f2bf(rA[1].z); f0[7] = f2bf(rA[1].w);
      f1[0] = f2bf(rA[2].x); f1[1] = f2bf(rA[2].y); f1[2] = f2bf(rA[2].z); f1[3] = f2bf(rA[2].w);
      f1[4] = f2bf(rA[3].x); f1[5] = f2bf(rA[3].y); f1[6] = f2bf(rA[3].z); f1[7] = f2bf(rA[3].w);
      *(bf16x8*)(aw0 + (kt & 1) * 4096)       = f0;
      *(bf16x8*)(aw0 + (kt & 1) * 4096 + 128) = f1;
    }

    // prefetch A(kt+1): stays in flight across the barrier (no vmcnt drain)
    if (kt < 7) {
      const float* an = aptr + (kt + 1) * 64;
      #pragma unroll
      for (int i = 0; i < 4; i++) rA[i] = *(const float4*)(an + i * 4);
    }

    // fence ONLY the LDS write; raw barrier (no implicit vmcnt(0) drain)
    asm volatile("s_waitcnt lgkmcnt(0)" ::: "memory");
    __builtin_amdgcn_s_barrier();
    __builtin_amdgcn_sched_barrier(0);

    const short* ab = &As[(kt & 1) * 4096];
    #pragma unroll
    for (int kc = 0; kc < 2; kc++) {
      bf16x8 a[4];
      #pragma unroll
      for (int mi = 0; mi < 4; mi++)
        a[mi] = *(const bf16x8*)&ab[((kc * 4 + mi) * 64 + lane) * 8];
      #pragma unroll
      for (int mi = 0; mi < 4; mi++)
        #pragma unroll
        for (int tj = 0; tj < 4; tj++)
          acc[mi][tj] = __builtin_amdgcn_mfma_f32_16x16x32_bf16(a[mi], b[kc][tj], acc[mi][tj], 0, 0, 0);
    }
  }

  // Epilogue: tanh(acc + hid_pb)·v_w, 16-lane reduce, LDS-combine 4 n-waves
  // -> one atomic per row per block (2 n-blocks per score point).
  __syncthreads();
  float* part = (float*)As;  // [row 0..63][wv 0..3]
  #pragma unroll
  for (int ti = 0; ti < 4; ti++) {
    #pragma unroll
    for (int r = 0; r < 4; r++) {
      int m = m0 + ti * 16 + quad * 4 + r;
      int b = m & (B_ - 1);
      float sum = 0.f;
      #pragma unroll
      for (int tj = 0; tj < 4; tj++) {
        int n = n0 + wv * 64 + tj * 16 + l15;
        float v = acc[ti][tj][r] + hid_pb[b * H_ + n];
        sum += fast_tanh(v) * v_w[n];
      }
      sum += __shfl_xor(sum, 1);
      sum += __shfl_xor(sum, 2);
      sum += __shfl_xor(sum, 4);
      sum += __shfl_xor(sum, 8);
      if (l15 == 0) part[(ti * 16 + quad * 4 + r) * 4 + wv] = sum;
    }
  }
  __syncthreads();
  if (tid < 64) {
    float s4 = part[tid * 4 + 0] + part[tid * 4 + 1] + part[tid * 4 + 2] + part[tid * 4 + 3];
    int m = m0 + tid;
    atomicAdd(scores + (m & (B_ - 1)) * S_ + (m >> 8), s4);
  }
}

// ---------------------------------------------------------------------------
// GRU input/hidden GEMMs share one launch (z-dim).
// ---------------------------------------------------------------------------
__global__ __launch_bounds__(256) void gemm_gru(
    const float* __restrict__ xb, const float* __restrict__ w_ih,
    const float* __restrict__ b_ih, float* __restrict__ gi,
    const float* __restrict__ hid, const float* __restrict__ w_hh,
    const float* __restrict__ b_hh, float* __restrict__ gh)
{
  __shared__ float As[16][65];
  __shared__ float Bs[16][65];
  if (blockIdx.z == 0) gemm_bt_dev(As, Bs, xb, w_ih, b_ih, gi, B_, 1536, RNNIN_);
  else                 gemm_bt_dev(As, Bs, hid, w_hh, b_hh, gh, B_, 1536, H_);
}

// ---------------------------------------------------------------------------
// Logits GEMM: C(256,30000) = h1 @ fc_id_w + b.  (unchanged)
// ---------------------------------------------------------------------------
__global__ __launch_bounds__(256, 4) void logits_gemm(
    const unsigned short* __restrict__ Ab, const float* __restrict__ Bw,
    const float* __restrict__ bias, float* __restrict__ C)
{
  __shared__ short As[2 * 16 * 64 * 8];   // [c][mt][lane][8] = 32 KB
  __shared__ short Bs[2 * 4 * 64 * 8];    // [c][tj][lane][8] = 8 KB
  const int n0 = blockIdx.x * 64;
  const int tid = threadIdx.x;
  const int lane = tid & 63;
  const int wv = tid >> 6;
  const int quad = lane >> 4, l15 = lane & 15;

  f32x4 acc[4][4];
  #pragma unroll
  for (int i = 0; i < 4; i++)
    #pragma unroll
    for (int j = 0; j < 4; j++) acc[i][j] = f32x4{0.f, 0.f, 0.f, 0.f};

  const int nB  = tid & 63;
  const int kg  = tid >> 6;
  const int cB  = kg >> 1;
  const int q0  = (kg & 1) * 2;
  const int tjB = nB >> 4;
  const bool nOK = (n0 + nB) < V_;

  for (int kt = 0; kt < 8; kt++) {
    const int kb = kt * 64;
    __syncthreads();
    #pragma unroll
    for (int p = 0; p < 8; p++) {
      int m = p * 32 + (tid >> 3), f = tid & 7;
      int c = f >> 2, q = f & 3;
      bf16x8 v = *(const bf16x8*)(Ab + (size_t)m * H_ + kb + c * 32 + q * 8);
      int mt = m >> 4, ld = q * 16 + (m & 15);
      *(bf16x8*)&As[((c * 16 + mt) * 64 + ld) * 8] = v;
    }
    {
      float col[16];
      const float* src = Bw + (size_t)(kb + kg * 16) * V_ + n0 + nB;
      #pragma unroll
      for (int i = 0; i < 16; i++) col[i] = nOK ? src[(size_t)i * V_] : 0.f;
      bf16x8 f0, f1;
      #pragma unroll
      for (int i = 0; i < 8; i++) { f0[i] = f2bf(col[i]); f1[i] = f2bf(col[8 + i]); }
      int ld0 = q0 * 16 + (nB & 15);
      *(bf16x8*)&Bs[((cB * 4 + tjB) * 64 + ld0) * 8] = f0;
      *(bf16x8*)&Bs[((cB * 4 + tjB) * 64 + ld0 + 16) * 8] = f1;
    }
    __syncthreads();
    #pragma unroll
    for (int c = 0; c < 2; c++) {
      bf16x8 a[4], b[4];
      #pragma unroll
      for (int ti = 0; ti < 4; ti++)
        a[ti] = *(const bf16x8*)&As[((c * 16 + wv * 4 + ti) * 64 + lane) * 8];
      #pragma unroll
      for (int tj = 0; tj < 4; tj++)
        b[tj] = *(const bf16x8*)&Bs[((c * 4 + tj) * 64 + lane) * 8];
      #pragma unroll
      for (int ti = 0; ti < 4; ti++)
        #pragma unroll
        for (int tj = 0; tj < 4; tj++)
          acc[ti][tj] = __builtin_amdgcn_mfma_f32_16x16x32_bf16(a[ti], b[tj], acc[ti][tj], 0, 0, 0);
    }
  }
  #pragma unroll
  for (int ti = 0; ti < 4; ti++)
    #pragma unroll
    for (int r = 0; r < 4; r++) {
      int m = wv * 64 + ti * 16 + quad * 4 + r;
      #pragma unroll
      for (int tj = 0; tj < 4; tj++) {
        int n = n0 + tj * 16 + l15;
        if (n < V_) C[(size_t)m * V_ + n] = acc[ti][tj][r] + bias[n];
      }
    }
}

// --------------------------- small kernels ---------------------------------
__global__ __launch_bounds__(256) void attn_softmax(
    const float* __restrict__ scores, const int* __restrict__ mask, float* __restrict__ aw)
{
  int b = blockIdx.x, tid = threadIdx.x;
  __shared__ float red[256];
  float v0 = scores[b * S_ + tid];
  float v1 = scores[b * S_ + tid + 256];
  if (mask[b * S_ + tid] == 0) v0 = -1e10f;
  if (mask[b * S_ + tid + 256] == 0) v1 = -1e10f;
  red[tid] = fmaxf(v0, v1);
  __syncthreads();
  for (int off = 128; off; off >>= 1) { if (tid < off) red[tid] = fmaxf(red[tid], red[tid + off]); __syncthreads(); }
  float mx = red[0];
  __syncthreads();
  float e0 = __expf(v0 - mx), e1 = __expf(v1 - mx);
  red[tid] = e0 + e1;
  __syncthreads();
  for (int off = 128; off; off >>= 1) { if (tid < off) red[tid] += red[tid + off]; __syncthreads(); }
  float inv = 1.f / red[0];
  aw[b * S_ + tid] = e0 * inv;
  aw[b * S_ + tid + 256] = e1 * inv;
}

// S split into 8 chunks -> 2048 blocks; deterministic partials into wpart.
__global__ __launch_bounds__(512) void attn_weighted_part(
    const float* __restrict__ aw, const float* __restrict__ enc, float* __restrict__ wpart)
{
  int b = blockIdx.x, c = blockIdx.y, h = threadIdx.x;
  __shared__ float a_s[64];
  if (h < 64) a_s[h] = aw[b * S_ + c * 64 + h];
  __syncthreads();
  const float* ep = enc + ((size_t)(c * 64) * B_ + b) * H_ + h;
  float acc = 0.f;
  #pragma unroll 8
  for (int s = 0; s < 64; s++)
    acc += a_s[s] * ep[(size_t)s * B_ * H_];
  wpart[((size_t)c * B_ + b) * H_ + h] = acc;
}

__global__ void build_x(const float* __restrict__ wpart, const int* __restrict__ ids,
                        const float* __restrict__ emb, const float* __restrict__ rate,
                        float* __restrict__ x)
{
  int i = blockIdx.x * 256 + threadIdx.x;
  if (i >= B_ * RNNIN_) return;
  int b = i / RNNIN_, j = i % RNNIN_;
  float v;
  if (j < H_) {
    size_t o = (size_t)b * H_ + j;
    const size_t st = (size_t)B_ * H_;
    v = 0.f;
    #pragma unroll
    for (int c = 0; c < 8; c++) v += wpart[o + c * st];
  }
  else if (j < H_ + E_) v = emb[(size_t)ids[b] * E_ + (j - H_)];
  else v = rate[b];
  x[i] = v;
}

__global__ void gru_gates(const float* __restrict__ gi, const float* __restrict__ gh,
                          const float* __restrict__ h0, float* __restrict__ h1,
                          unsigned short* __restrict__ h1b, float* __restrict__ h1_out)
{
  int i = blockIdx.x * 256 + threadIdx.x;  // B*H
  int b = i >> 9, j = i & (H_ - 1);
  const float* gib = gi + (size_t)b * 1536;
  const float* ghb = gh + (size_t)b * 1536;
  float r = sigmoidf(gib[j] + ghb[j]);
  float z = sigmoidf(gib[512 + j] + ghb[512 + j]);
  float n = fast_tanh(gib[1024 + j] + r * ghb[1024 + j]);
  float h = (1.f - z) * n + z * h0[i];
  h1[i] = h;
  h1b[i] = (unsigned short)f2bf(h);
  h1_out[i] = h;
}

__global__ __launch_bounds__(1024) void softmax_fused(
    float* __restrict__ lp, const float* __restrict__ cv, int* __restrict__ maxid)
{
  int b = blockIdx.x, tid = threadIdx.x;
  int wid = tid >> 6, lane = tid & 63;
  float* row = lp + (size_t)b * V_;
  const float* cvr = cv + (size_t)b * V_;
  __shared__ float redf[16];
  __shared__ float rede[16];
  __shared__ int   redi[16];

  float mx = -INFINITY;
  for (int v = tid; v < V_; v += 1024) mx = fmaxf(mx, row[v]);
  #pragma unroll
  for (int o = 1; o < 64; o <<= 1) mx = fmaxf(mx, __shfl_xor(mx, o));
  if (lane == 0) redf[wid] = mx;
  __syncthreads();
  if (tid == 0) {
    float m = redf[0];
    for (int i = 1; i < 16; i++) m = fmaxf(m, redf[i]);
    redf[0] = m;
  }
  __syncthreads();
  float M = redf[0];
  __syncthreads();

  float s = 0.f, best = -1.f;
  int bi = 0;
  for (int v = tid; v < V_; v += 1024) {
    float e = __expf(row[v] - M) * cvr[v];
    row[v] = e;
    s += e;
    if (e > best) { best = e; bi = v; }
  }
  #pragma unroll
  for (int o = 1; o < 64; o <<= 1) {
    s += __shfl_xor(s, o);
    float ob = __shfl_xor(best, o);
    int oi = __shfl_xor(bi, o);
    if (ob > best || (ob == best && oi < bi)) { best = ob; bi = oi; }
  }
  if (lane == 0) { redf[wid] = s; rede[wid] = best; redi[wid] = bi; }
  __syncthreads();
  if (tid == 0) {
    float ss = 0.f, bb = rede[0];
    int ii = redi[0];
    for (int i = 0; i < 16; i++) {
      ss += redf[i];
      if (rede[i] > bb || (rede[i] == bb && redi[i] < ii)) { bb = rede[i]; ii = redi[i]; }
    }
    redf[0] = ss;
    maxid[b] = ii;
  }
  __syncthreads();
  float inv = 1.f / redf[0];
  for (int v = tid; v < V_; v += 1024) {
    float p = row[v] * inv;
    p = fminf(fmaxf(p, 1e-6f), 1.f);
    row[v] = __logf(p);
  }
}

// Tandem GEMM with fused A-gather ([emb[maxid], h1]) and relu.
// C(256,512) = A(256,640) @ tan_w(640,512) + tan_b.
__global__ __launch_bounds__(256) void tandem_gemm(
    const int* __restrict__ maxid, const float* __restrict__ emb,
    const float* __restrict__ h1, const float* __restrict__ tan_w,
    const float* __restrict__ tan_b, float* __restrict__ rate_in)
{
  __shared__ float As[16][65];
  __shared__ float Bs[16][65];
  const int m0 = blockIdx.x * 64, n0 = blockIdx.y * 64;
  const int tid = threadIdx.x;
  const int tx = tid & 15, ty = tid >> 4;
  float acc[4][4] = {};
  for (int k0 = 0; k0 < 640; k0 += 16) {
    __syncthreads();
    #pragma unroll
    for (int i = 0; i < 4; i++) {
      int e = tid + i * 256;
      int m = e >> 4, kk = e & 15;
      int mm = m0 + m, k = k0 + kk;
      float v = (k < E_) ? emb[(size_t)maxid[mm] * E_ + k]
                         : h1[(size_t)mm * H_ + (k - E_)];
      As[kk][m] = v;
    }
    #pragma unroll
    for (int i = 0; i < 4; i++) {
      int e = tid + i * 256;
      int k = e >> 6, n = e & 63;
      Bs[k][n] = tan_w[(size_t)(k0 + k) * H_ + n0 + n];
    }
    __syncthreads();
    #pragma unroll
    for (int k = 0; k < 16; k++) {
      float a[4], b[4];
      #pragma unroll
      for (int i = 0; i < 4; i++) a[i] = As[k][ty * 4 + i];
      #pragma unroll
      for (int j = 0; j < 4; j++) b[j] = Bs[k][tx * 4 + j];
      #pragma unroll
      for (int i = 0; i < 4; i++)
        #pragma unroll
        for (int j = 0; j < 4; j++) acc[i][j] += a[i] * b[j];
    }
  }
  #pragma unroll
  for (int i = 0; i < 4; i++) {
    int m = m0 + ty * 4 + i;
    #pragma unroll
    for (int j = 0; j < 4; j++) {
      int n = n0 + tx * 4 + j;
      rate_in[(size_t)m * H_ + n] = fmaxf(acc[i][j] + tan_b[n], 0.f);
    }
  }
}

__global__ __launch_bounds__(64) void rate_head(const float* __restrict__ rate_in,
                                                const float* __restrict__ rate_w,
                                                const float* __restrict__ rate_b,
                                                float* __restrict__ out)
{
  int b = blockIdx.x, t = threadIdx.x;
  float s = 0.f;
  #pragma unroll
  for (int i = 0; i < 8; i++) s += rate_in[b * H_ + t + 64 * i] * rate_w[t + 64 * i];
  #pragma unroll
  for (int m = 32; m; m >>= 1) s += __shfl_xor(s, m);
  if (t == 0) out[b] = sigmoidf(s + rate_b[0]);
}

// ---------------------------------------------------------------------------
extern "C" void kernel_launch(void* const* d_in, const int* in_sizes, int n_in,
                              void* d_out, int out_size, void* d_ws, size_t ws_size,
                              hipStream_t stream)
{
  const int*   input_id   = (const int*)  d_in[0];
  const float* input_rate = (const float*)d_in[1];
  const float* hidden     = (const float*)d_in[2];
  const float* enc        = (const float*)d_in[3];
  const int*   attn_mask  = (const int*)  d_in[4];
  const float* cv         = (const float*)d_in[5];
  const float* emb        = (const float*)d_in[6];
  const float* attn_w     = (const float*)d_in[7];
  const float* attn_b     = (const float*)d_in[8];
  const float* v_w        = (const float*)d_in[9];
  const float* w_ih       = (const float*)d_in[10];
  const float* w_hh       = (const float*)d_in[11];
  const float* b_ih       = (const float*)d_in[12];
  const float* b_hh       = (const float*)d_in[13];
  const float* fc_w       = (const float*)d_in[14];
  const float* fc_b       = (const float*)d_in[15];
  const float* tan_w      = (const float*)d_in[16];
  const float* tan_b      = (const float*)d_in[17];
  const float* rate_w     = (const float*)d_in[18];
  const float* rate_b     = (const float*)d_in[19];

  float* out = (float*)d_out;
  float* ws  = (float*)d_ws;
  // ws layout (float offsets)
  float* hid_pb   = ws;                   // [0,       131072)
  float* scores   = ws + 131072;          // [131072,  262144)
  float* aw       = ws + 262144;          // [262144,  393216)
  float* xbuf     = ws + 524288;          // [524288,  688384)  B*641
  float* gi       = ws + 688384;          // [688384, 1081600)  B*1536
  float* gh       = ws + 1081600;         // [1081600,1474816)  B*1536
  float* h1       = ws + 1474816;         // [1474816,1605888)  B*H
  float* rate_in  = ws + 1605888;         // [1605888,1736960)  B*H
  int*   maxid    = (int*)(ws + 1736960); // [1736960,1737216)  B ints
  unsigned short* Btf = (unsigned short*)(ws + 1737216); // 512KB packed B
  unsigned short* h1b = (unsigned short*)(ws + 1868288); // 256*512 bf16
  // wpart: 8*B*H floats = 1,048,576 -> overlays [gi .. rate_in end) exactly;
  // consumed by build_x BEFORE gemm_gru/gru_gates/tandem write that region.
  float* wpart = gi;

  float* out_pred = out;
  float* out_rate = out + (size_t)B_ * V_;
  float* out_h1   = out + (size_t)B_ * V_ + B_;

  hipMemsetAsync(scores, 0, (size_t)B_ * S_ * sizeof(float), stream);

  prep_fused<<<1056, 256, 0, stream>>>(attn_w, Btf, hidden, attn_b, hid_pb);

  attn_gemm_score<<<4096, 256, 0, stream>>>(enc, Btf, hid_pb, v_w, scores);

  attn_softmax<<<B_, 256, 0, stream>>>(scores, attn_mask, aw);
  attn_weighted_part<<<dim3(B_, 8), 512, 0, stream>>>(aw, enc, wpart);
  build_x<<<641, 256, 0, stream>>>(wpart, input_id, emb, input_rate, xbuf);

  gemm_gru<<<dim3(4, 24, 2), 256, 0, stream>>>(xbuf, w_ih, b_ih, gi, hidden, w_hh, b_hh, gh);
  gru_gates<<<512, 256, 0, stream>>>(gi, gh, hidden, h1, h1b, out_h1);

  logits_gemm<<<469, 256, 0, stream>>>(h1b, fc_w, fc_b, out_pred);
  softmax_fused<<<B_, 1024, 0, stream>>>(out_pred, cv, maxid);

  tandem_gemm<<<dim3(4, 8), 256, 0, stream>>>(maxid, emb, h1, tan_w, tan_b, rate_in);
  rate_head<<<B_, 64, 0, stream>>>(rate_in, rate_w, rate_b, out_rate);
}